// Round 4
// baseline (83.730 us; speedup 1.0000x reference)
//
#include <hip/hip_runtime.h>
#include <hip/hip_fp16.h>

typedef __bf16 bf16x8 __attribute__((ext_vector_type(8)));
typedef float floatx16 __attribute__((ext_vector_type(16)));
typedef unsigned int uint;
typedef unsigned short ushort;

constexpr int Mdim = 256, Ndim = 8192, Kdim = 8192;
constexpr int BN = 32, BK = 64, KSPLIT = 4;
constexpr int KS = Kdim / KSPLIT;    // 2048 per block
constexpr int NT = KS / BK;          // 32 K-steps
constexpr int KB = Kdim / 256;       // 32 q4k blocks per weight row

union UB { uint u[4]; bf16x8 v; };

__device__ __forceinline__ uint cvtpk(float lo, float hi) {
  uint r; asm("v_cvt_pk_bf16_f32 %0, %1, %2" : "=v"(r) : "v"(lo), "v"(hi));
  return r;
}

// B LDS: 32 rows x 64 ushort (128B row); XOR-swizzle 16B chunks across banks
__device__ __forceinline__ int bswz(int row, int ch) {
  return row * 64 + ((ch ^ (row & 7)) << 3);
}

template<bool PRE>
__global__ __launch_bounds__(256, 2)
void q4k_gemm(const float* __restrict__ x, const bf16x8* __restrict__ xbf,
              const int* __restrict__ qw, const float* __restrict__ bias,
              float* __restrict__ out)
{
  __shared__ ushort Bb[2][BN * 64];   // 4 KB each, double-buffered

  const int tid = threadIdx.x;
  const int bid = blockIdx.x;
  // bijective XCD swizzle: the 4 ks-siblings of one n-tile share an XCD
  const int l  = (bid & 7) * 128 + (bid >> 3);
  const int nb = l >> 2;
  const int ks = l & 3;
  const int n0 = nb * BN;
  const int ks8 = ks * (KS >> 8);

  const int sr = tid >> 3;   // B row 0..31
  const int sq = tid & 7;    // byte-quad within 32B qs group

  const int lane = tid & 63;
  const int wave = tid >> 6;
  const int mb0  = wave * 2;       // two 32-row m-frags per wave
  const int brow = lane & 31;
  const int bco  = lane >> 5;

  const int* bp0 = qw + (n0 + sr) * (KB * 144);
  const bf16x8* xA0 = PRE ? (xbf + ((mb0    ) * 512 + ks * 128) * 64 + lane) : nullptr;
  const bf16x8* xA1 = PRE ? (xbf + ((mb0 + 1) * 512 + ks * 128) * 64 + lane) : nullptr;

  uint4 R[2];
  uint4 Mdd[2], M0[2], M1[2], M2[2];
  uint2 pq0, pq1;
  bf16x8 aA[8], aB[8];
  floatx16 acc0 = {}, acc1 = {};

  auto gloadB = [&](int s2, int rs, int ms, bool meta) {
    const int* bp = bp0 + (ks8 + (s2 >> 2)) * 144;
    R[rs] = *(const uint4*)(bp + 16 + (s2 & 3) * 32 + sq * 4);
    if (meta) {
      Mdd[ms] = *(const uint4*)bp;
      M0[ms]  = *(const uint4*)(bp + 4);
      M1[ms]  = *(const uint4*)(bp + 8);
      M2[ms]  = *(const uint4*)(bp + 12);
    }
  };

  auto gloadA = [&](int t, bf16x8 (&A)[8]) {
    if constexpr (PRE) {
      const int f = t * 4 * 64;
      #pragma unroll
      for (int kk = 0; kk < 4; ++kk) {
        A[kk]     = xA0[f + kk * 64];
        A[4 + kk] = xA1[f + kk * 64];
      }
    } else {
      const int kg = ks * KS + t * BK + bco * 8;
      #pragma unroll
      for (int kk = 0; kk < 4; ++kk) {
        const float4* fA = (const float4*)(x + (mb0 * 32 + brow) * Kdim + kg + kk * 16);
        const float4* fB = (const float4*)(x + ((mb0 + 1) * 32 + brow) * Kdim + kg + kk * 16);
        const float4 p0 = fA[0], p1 = fA[1], q0 = fB[0], q1 = fB[1];
        UB ua, ub;
        ua.u[0] = cvtpk(p0.x, p0.y); ua.u[1] = cvtpk(p0.z, p0.w);
        ua.u[2] = cvtpk(p1.x, p1.y); ua.u[3] = cvtpk(p1.z, p1.w);
        ub.u[0] = cvtpk(q0.x, q0.y); ub.u[1] = cvtpk(q0.z, q0.w);
        ub.u[2] = cvtpk(q1.x, q1.y); ub.u[3] = cvtpk(q1.z, q1.w);
        A[kk] = ua.v; A[4 + kk] = ub.v;
      }
    }
  };

  auto dequant = [&](int c, int rs, int ms) {
    const uint4 dd = Mdd[ms];
    const float d  = __half2float(__ushort_as_half((ushort)((dd.x & 255u) | ((dd.y & 255u) << 8))));
    const float dm = __half2float(__ushort_as_half((ushort)((dd.z & 255u) | ((dd.w & 255u) << 8))));
    const uint4 s0 = M0[ms], s1 = M1[ms], s2 = M2[ms];
    uint scA, scB, mnA, mnB;
    if (c == 0)      { scA = s0.x & 63u; scB = s0.y & 63u; mnA = s1.x & 63u; mnB = s1.y & 63u; }
    else if (c == 1) { scA = s0.z & 63u; scB = s0.w & 63u; mnA = s1.z & 63u; mnB = s1.w & 63u; }
    else if (c == 2) {
      scA = (s2.x & 15u) | ((s0.x >> 2) & 48u); scB = (s2.y & 15u) | ((s0.y >> 2) & 48u);
      mnA = (s2.x >> 4)  | ((s1.x >> 2) & 48u); mnB = (s2.y >> 4)  | ((s1.y >> 2) & 48u);
    } else {
      scA = (s2.z & 15u) | ((s0.z >> 2) & 48u); scB = (s2.w & 15u) | ((s0.w >> 2) & 48u);
      mnA = (s2.z >> 4)  | ((s1.z >> 2) & 48u); mnB = (s2.w >> 4)  | ((s1.w >> 2) & 48u);
    }
    const float dlA = d * (float)scA, mlA = dm * (float)mnA;
    const float dlB = d * (float)scB, mlB = dm * (float)mnB;
    const uint4 qv = R[rs];
    const float w0 = fmaf(dlA, (float)(qv.x & 15u), -mlA);
    const float w1 = fmaf(dlA, (float)(qv.y & 15u), -mlA);
    const float w2 = fmaf(dlA, (float)(qv.z & 15u), -mlA);
    const float w3 = fmaf(dlA, (float)(qv.w & 15u), -mlA);
    const float h0 = fmaf(dlB, (float)(qv.x >> 4), -mlB);
    const float h1 = fmaf(dlB, (float)(qv.y >> 4), -mlB);
    const float h2 = fmaf(dlB, (float)(qv.z >> 4), -mlB);
    const float h3 = fmaf(dlB, (float)(qv.w >> 4), -mlB);
    pq0.x = cvtpk(w0, w1); pq0.y = cvtpk(w2, w3);
    pq1.x = cvtpk(h0, h1); pq1.y = cvtpk(h2, h3);
  };

  auto bwrite = [&](int bufi) {
    *(uint2*)&Bb[bufi][bswz(sr, (sq >> 1))     + (sq & 1) * 4] = pq0;
    *(uint2*)&Bb[bufi][bswz(sr, 4 + (sq >> 1)) + (sq & 1) * 4] = pq1;
  };

  auto mstep = [&](int bufi, const bf16x8 (&A)[8]) {
    #pragma unroll
    for (int kk = 0; kk < 4; ++kk) {
      const bf16x8 bq = *(const bf16x8*)&Bb[bufi][bswz(brow, kk * 2 + bco)];
      acc0 = __builtin_amdgcn_mfma_f32_32x32x16_bf16(A[kk],     bq, acc0, 0, 0, 0);
      acc1 = __builtin_amdgcn_mfma_f32_32x32x16_bf16(A[4 + kk], bq, acc1, 0, 0, 0);
    }
  };

  // prologue: B(0) staged to buf0; B(1) qs in regs; A(0),A(1) in regs
  gloadB(0, 0, 0, true);
  gloadB(1, 1, 0, false);
  gloadA(0, aA);
  gloadA(1, aB);
  dequant(0, 0, 0);
  bwrite(0);
  asm volatile("s_waitcnt lgkmcnt(0)" ::: "memory");
  __builtin_amdgcn_s_barrier();
  __builtin_amdgcn_sched_barrier(0);

  // steady state: one raw barrier per step, vmcnt NEVER drained in-loop.
  // gloadB(s+2) -> R[u&1]; dequant(s+1) <- R[(u+1)&1]; A refilled post-MFMA
  // (depth-2 cover). Meta block loaded 2+ steps ahead of first use.
  #define PH(u, CUR) {                                                       \
    const int s_ = base + (u);                                               \
    if (s_ + 2 < NT) gloadB(s_ + 2, (u) & 1, (((u) + 2) >> 2) & 1,           \
                            (((u) + 2) & 3) == 0);                           \
    if (s_ + 1 < NT) {                                                       \
      dequant(((u) + 1) & 3, ((u) + 1) & 1, (((u) + 1) >> 2) & 1);           \
      bwrite(((u) + 1) & 1);                                                 \
    }                                                                        \
    __builtin_amdgcn_s_setprio(1);                                           \
    mstep((u) & 1, CUR);                                                     \
    __builtin_amdgcn_s_setprio(0);                                           \
    if (s_ + 2 < NT) gloadA(s_ + 2, CUR);                                    \
    asm volatile("s_waitcnt lgkmcnt(0)" ::: "memory");                       \
    __builtin_amdgcn_s_barrier();                                            \
    __builtin_amdgcn_sched_barrier(0);                                       \
  }

  for (int base = 0; base < NT; base += 8) {
    PH(0, aA) PH(1, aB) PH(2, aA) PH(3, aB)
    PH(4, aA) PH(5, aB) PH(6, aA) PH(7, aB)
  }
  #undef PH

  // epilogue: D layout col=lane&31, row=(r&3)+8*(r>>2)+4*(lane>>5)  [m74/m101]
  const int gn = n0 + (lane & 31);
  const float bv = (ks == 0) ? bias[gn] : 0.0f;
  const int mrow = wave * 64 + 4 * (lane >> 5);
  #pragma unroll
  for (int r = 0; r < 16; ++r) {
    const int m = mrow + (r & 3) + 8 * (r >> 2);
    atomicAdd(&out[m * Ndim + gn], acc0[r] + bv);
  }
  #pragma unroll
  for (int r = 0; r < 16; ++r) {
    const int m = mrow + 32 + (r & 3) + 8 * (r >> 2);
    atomicAdd(&out[m * Ndim + gn], acc1[r] + bv);
  }
}

// zero d_out (atomic accumulate target) and optionally pre-tile x -> bf16
// MFMA-fragment layout: xb[(mb*512+kb)*64+lane] = 16B frag slice,
// m = mb*32+(lane&31), k = kb*16+(lane>>5)*8
template<bool DOCVT>
__global__ __launch_bounds__(256)
void prep(const float* __restrict__ x, uint4* __restrict__ xb,
          float4* __restrict__ out)
{
  const int gid = blockIdx.x * 256 + threadIdx.x;
  out[gid * 2]     = float4{0.f, 0.f, 0.f, 0.f};
  out[gid * 2 + 1] = float4{0.f, 0.f, 0.f, 0.f};
  if (DOCVT) {
    const int lane = gid & 63;
    const int m = ((gid >> 15) * 32) + (lane & 31);
    const int k = (((gid >> 6) & 511) * 16) + (lane >> 5) * 8;
    const float4* p = (const float4*)(x + m * Kdim + k);
    const float4 f0 = p[0], f1 = p[1];
    uint4 st;
    st.x = cvtpk(f0.x, f0.y); st.y = cvtpk(f0.z, f0.w);
    st.z = cvtpk(f1.x, f1.y); st.w = cvtpk(f1.z, f1.w);
    xb[gid] = st;
  }
}

extern "C" void kernel_launch(void* const* d_in, const int* in_sizes, int n_in,
                              void* d_out, int out_size, void* d_ws, size_t ws_size,
                              hipStream_t stream) {
  (void)in_sizes; (void)n_in; (void)out_size;
  const float* x    = (const float*)d_in[0];
  const int*   qw   = (const int*)d_in[1];
  const float* bias = (const float*)d_in[2];
  float* out = (float*)d_out;

  const size_t need = (size_t)Mdim * Kdim * 2;   // 4 MB bf16 fragment tiles
  if (ws_size >= need) {
    prep<true><<<1024, 256, 0, stream>>>(x, (uint4*)d_ws, (float4*)out);
    q4k_gemm<true><<<1024, 256, 0, stream>>>(x, (const bf16x8*)d_ws, qw, bias, out);
  } else {
    prep<false><<<1024, 256, 0, stream>>>(x, nullptr, (float4*)out);
    q4k_gemm<false><<<1024, 256, 0, stream>>>(x, nullptr, qw, bias, out);
  }
}

// Round 6
// 71.140 us; speedup vs baseline: 1.1770x; 1.1770x over previous
//
#include <hip/hip_runtime.h>
#include <hip/hip_fp16.h>

typedef __bf16 bf16x8 __attribute__((ext_vector_type(8)));
typedef float floatx16 __attribute__((ext_vector_type(16)));
typedef unsigned int uint;
typedef unsigned short ushort;
typedef uint  uintx4  __attribute__((ext_vector_type(4)));
typedef float floatx4 __attribute__((ext_vector_type(4)));

constexpr int Mdim = 256, Ndim = 8192, Kdim = 8192;
constexpr int BN = 64, BK = 64, KSPLIT = 4;
constexpr int KS = Kdim / KSPLIT;    // 2048 per block
constexpr int NT = KS / BK;          // 32 K-steps
constexpr int KB = Kdim / 256;       // 32 q4k blocks per weight row

union U8 { uint u[4]; bf16x8 v; };

__device__ __forceinline__ uint cvtpk(float lo, float hi) {
  uint r; asm("v_cvt_pk_bf16_f32 %0, %1, %2" : "=v"(r) : "v"(lo), "v"(hi));
  return r;
}

// explicit global (addrspace(1)) loads: guaranteed global_load_* (vmcnt-only,
// never flat). flat_* would increment lgkmcnt and get drained at our barrier.
// NOTE: T must be a trivial (ext_vector) type, not a HIP_vector_type class.
template <typename T>
__device__ __forceinline__ T gld(const void* p) {
  return *(const __attribute__((address_space(1))) T*)p;
}

// B LDS: 64 rows x 64 ushort (128B row); XOR-swizzle 16B chunks across banks
__device__ __forceinline__ int bswz(int row, int ch) {
  return row * 64 + ((ch ^ (row & 7)) << 3);
}

template<bool PRE>
__global__ __launch_bounds__(256, 2)
void q4k_gemm(const float* __restrict__ x, const bf16x8* __restrict__ xbf,
              const int* __restrict__ qw, const float* __restrict__ bias,
              float* __restrict__ out)
{
  __shared__ ushort Bb[2][BN * 64];   // 8 KB each, double-buffered

  const int tid = threadIdx.x;
  const int bid = blockIdx.x;
  // bijective XCD swizzle (512 blocks): ks-siblings of one n-tile co-XCD
  const int l  = (bid & 7) * 64 + (bid >> 3);
  const int nb = l >> 2;              // 0..127
  const int ks = l & 3;
  const int n0 = nb * BN;
  const int ks8 = ks * (KS >> 8);

  const int sr = tid >> 2;   // B row 0..63
  const int sq = tid & 3;    // 8-int slice within the 32-int qs group

  const int lane = tid & 63;
  const int wave = tid >> 6;
  const int mb0  = wave * 2;       // two 32-row m-frags per wave
  const int brow = lane & 31;
  const int bco  = lane >> 5;

  const int* bp0 = qw + (n0 + sr) * (KB * 144);
  const bf16x8* xA0 = PRE ? (xbf + ((mb0    ) * 512 + ks * 128) * 64 + lane) : nullptr;
  const bf16x8* xA1 = PRE ? (xbf + ((mb0 + 1) * 512 + ks * 128) * 64 + lane) : nullptr;

  uintx4 R[4][2];                        // 3-phase-deep qs prefetch ring
  uintx4 Mdd[2], M0[2], M1[2], M2[2];    // meta, 4-step granularity, 2 slots
  U8 pqL, pqH;
  bf16x8 aA[8], aB[8];
  floatx16 acc00 = {}, acc01 = {}, acc10 = {}, acc11 = {};

  auto gloadB = [&](int s2, int rs, int ms, bool meta) {
    const int* bp = bp0 + (ks8 + (s2 >> 2)) * 144;
    const int* qp = bp + 16 + (s2 & 3) * 32 + sq * 8;
    R[rs][0] = gld<uintx4>(qp);
    R[rs][1] = gld<uintx4>(qp + 4);
    if (meta) {
      Mdd[ms] = gld<uintx4>(bp);
      M0[ms]  = gld<uintx4>(bp + 4);
      M1[ms]  = gld<uintx4>(bp + 8);
      M2[ms]  = gld<uintx4>(bp + 12);
    }
  };

  auto gloadA = [&](int t, bf16x8 (&A)[8]) {
    if constexpr (PRE) {
      const int f = t * 4 * 64;
      #pragma unroll
      for (int kk = 0; kk < 4; ++kk) {
        A[kk]     = gld<bf16x8>(xA0 + f + kk * 64);
        A[4 + kk] = gld<bf16x8>(xA1 + f + kk * 64);
      }
    } else {
      const int kg = ks * KS + t * BK + bco * 8;
      #pragma unroll
      for (int kk = 0; kk < 4; ++kk) {
        const float* fA = x + (mb0 * 32 + brow) * Kdim + kg + kk * 16;
        const float* fB = x + ((mb0 + 1) * 32 + brow) * Kdim + kg + kk * 16;
        const floatx4 p0 = gld<floatx4>(fA), p1 = gld<floatx4>(fA + 4);
        const floatx4 q0 = gld<floatx4>(fB), q1 = gld<floatx4>(fB + 4);
        U8 ua, ub;
        ua.u[0] = cvtpk(p0.x, p0.y); ua.u[1] = cvtpk(p0.z, p0.w);
        ua.u[2] = cvtpk(p1.x, p1.y); ua.u[3] = cvtpk(p1.z, p1.w);
        ub.u[0] = cvtpk(q0.x, q0.y); ub.u[1] = cvtpk(q0.z, q0.w);
        ub.u[2] = cvtpk(q1.x, q1.y); ub.u[3] = cvtpk(q1.z, q1.w);
        A[kk] = ua.v; A[4 + kk] = ub.v;
      }
    }
  };

  auto dequant = [&](int c, int rs, int ms) {
    const uintx4 dd = Mdd[ms];
    const float d  = __half2float(__ushort_as_half((ushort)((dd.x & 255u) | ((dd.y & 255u) << 8))));
    const float dm = __half2float(__ushort_as_half((ushort)((dd.z & 255u) | ((dd.w & 255u) << 8))));
    const uintx4 s0 = M0[ms], s1 = M1[ms], s2 = M2[ms];
    uint scA, scB, mnA, mnB;
    if (c == 0)      { scA = s0.x & 63u; scB = s0.y & 63u; mnA = s1.x & 63u; mnB = s1.y & 63u; }
    else if (c == 1) { scA = s0.z & 63u; scB = s0.w & 63u; mnA = s1.z & 63u; mnB = s1.w & 63u; }
    else if (c == 2) {
      scA = (s2.x & 15u) | ((s0.x >> 2) & 48u); scB = (s2.y & 15u) | ((s0.y >> 2) & 48u);
      mnA = (s2.x >> 4)  | ((s1.x >> 2) & 48u); mnB = (s2.y >> 4)  | ((s1.y >> 2) & 48u);
    } else {
      scA = (s2.z & 15u) | ((s0.z >> 2) & 48u); scB = (s2.w & 15u) | ((s0.w >> 2) & 48u);
      mnA = (s2.z >> 4)  | ((s1.z >> 2) & 48u); mnB = (s2.w >> 4)  | ((s1.w >> 2) & 48u);
    }
    const float dlA = d * (float)scA, mlA = dm * (float)mnA;
    const float dlB = d * (float)scB, mlB = dm * (float)mnB;
    float wl[8], wh[8];
    #pragma unroll
    for (int h = 0; h < 2; ++h) {
      const uintx4 qv = R[rs][h];
      wl[h*4+0] = fmaf(dlA, (float)(qv.x & 15u), -mlA);
      wl[h*4+1] = fmaf(dlA, (float)(qv.y & 15u), -mlA);
      wl[h*4+2] = fmaf(dlA, (float)(qv.z & 15u), -mlA);
      wl[h*4+3] = fmaf(dlA, (float)(qv.w & 15u), -mlA);
      wh[h*4+0] = fmaf(dlB, (float)(qv.x >> 4), -mlB);
      wh[h*4+1] = fmaf(dlB, (float)(qv.y >> 4), -mlB);
      wh[h*4+2] = fmaf(dlB, (float)(qv.z >> 4), -mlB);
      wh[h*4+3] = fmaf(dlB, (float)(qv.w >> 4), -mlB);
    }
    #pragma unroll
    for (int p = 0; p < 4; ++p) {
      pqL.u[p] = cvtpk(wl[2*p], wl[2*p+1]);
      pqH.u[p] = cvtpk(wh[2*p], wh[2*p+1]);
    }
  };

  auto bwrite = [&](int bufi) {
    *(bf16x8*)&Bb[bufi][bswz(sr, sq)]     = pqL.v;   // lo nibbles: k chunk sq
    *(bf16x8*)&Bb[bufi][bswz(sr, 4 + sq)] = pqH.v;   // hi nibbles: k chunk 4+sq
  };

  auto mstep = [&](int bufi, const bf16x8 (&A)[8]) {
    #pragma unroll
    for (int kk = 0; kk < 4; ++kk) {
      const bf16x8 bq0 = *(const bf16x8*)&Bb[bufi][bswz(brow,      kk * 2 + bco)];
      const bf16x8 bq1 = *(const bf16x8*)&Bb[bufi][bswz(brow + 32, kk * 2 + bco)];
      acc00 = __builtin_amdgcn_mfma_f32_32x32x16_bf16(A[kk],     bq0, acc00, 0, 0, 0);
      acc01 = __builtin_amdgcn_mfma_f32_32x32x16_bf16(A[kk],     bq1, acc01, 0, 0, 0);
      acc10 = __builtin_amdgcn_mfma_f32_32x32x16_bf16(A[4 + kk], bq0, acc10, 0, 0, 0);
      acc11 = __builtin_amdgcn_mfma_f32_32x32x16_bf16(A[4 + kk], bq1, acc11, 0, 0, 0);
    }
  };

  // prologue: qs for steps 0..3, meta slot0 (steps 0-3), A for steps 0,1
  gloadB(0, 0, 0, true);
  gloadB(1, 1, 0, false);
  gloadB(2, 2, 0, false);
  gloadB(3, 3, 0, false);
  gloadA(0, aA);
  gloadA(1, aB);
  dequant(0, 0, 0);
  bwrite(0);
  asm volatile("s_waitcnt lgkmcnt(0)" ::: "memory");
  __builtin_amdgcn_s_barrier();
  __builtin_amdgcn_sched_barrier(0);

  // steady state: one raw barrier/step; vmcnt never drained in-loop.
  // qs cover = 3 phases (R ring of 4); meta cover = 3-6 phases; A cover = 2.
  #define PH(u, CUR) {                                                       \
    const int s_ = base + (u);                                               \
    if (s_ + 4 < NT) gloadB(s_ + 4, (u) & 3, (((u) + 4) >> 2) & 1,           \
                            (((u) + 4) & 3) == 0);                           \
    if (s_ + 1 < NT) {                                                       \
      dequant(((u) + 1) & 3, ((u) + 1) & 3, (((u) + 1) >> 2) & 1);           \
      bwrite(((u) + 1) & 1);                                                 \
    }                                                                        \
    __builtin_amdgcn_s_setprio(1);                                           \
    mstep((u) & 1, CUR);                                                     \
    __builtin_amdgcn_s_setprio(0);                                           \
    if (s_ + 2 < NT) gloadA(s_ + 2, CUR);                                    \
    asm volatile("s_waitcnt lgkmcnt(0)" ::: "memory");                       \
    __builtin_amdgcn_s_barrier();                                            \
    __builtin_amdgcn_sched_barrier(0);                                       \
  }

  for (int base = 0; base < NT; base += 8) {
    PH(0, aA) PH(1, aB) PH(2, aA) PH(3, aB)
    PH(4, aA) PH(5, aB) PH(6, aA) PH(7, aB)
  }
  #undef PH

  // epilogue: D layout col=lane&31, row=(r&3)+8*(r>>2)+4*(lane>>5)  [m74/m101]
  const int gn0 = n0 + (lane & 31);
  const int gn1 = gn0 + 32;
  const float bv0 = (ks == 0) ? bias[gn0] : 0.0f;
  const float bv1 = (ks == 0) ? bias[gn1] : 0.0f;
  const int mrow = wave * 64 + 4 * (lane >> 5);
  #pragma unroll
  for (int r = 0; r < 16; ++r) {
    const int m = mrow + (r & 3) + 8 * (r >> 2);
    atomicAdd(&out[m * Ndim + gn0], acc00[r] + bv0);
    atomicAdd(&out[m * Ndim + gn1], acc01[r] + bv1);
    atomicAdd(&out[(m + 32) * Ndim + gn0], acc10[r] + bv0);
    atomicAdd(&out[(m + 32) * Ndim + gn1], acc11[r] + bv1);
  }
}

// zero d_out (atomic accumulate target) and optionally pre-tile x -> bf16
// MFMA-fragment layout: xb[(mb*512+kb)*64+lane] = 16B frag slice,
// m = mb*32+(lane&31), k = kb*16+(lane>>5)*8
template<bool DOCVT>
__global__ __launch_bounds__(256)
void prep(const float* __restrict__ x, uintx4* __restrict__ xb,
          floatx4* __restrict__ out)
{
  const int gid = blockIdx.x * 256 + threadIdx.x;
  out[gid * 2]     = floatx4{0.f, 0.f, 0.f, 0.f};
  out[gid * 2 + 1] = floatx4{0.f, 0.f, 0.f, 0.f};
  if (DOCVT) {
    const int lane = gid & 63;
    const int m = ((gid >> 15) * 32) + (lane & 31);
    const int k = (((gid >> 6) & 511) * 16) + (lane >> 5) * 8;
    const floatx4 f0 = gld<floatx4>(x + m * Kdim + k);
    const floatx4 f1 = gld<floatx4>(x + m * Kdim + k + 4);
    uintx4 st;
    st.x = cvtpk(f0.x, f0.y); st.y = cvtpk(f0.z, f0.w);
    st.z = cvtpk(f1.x, f1.y); st.w = cvtpk(f1.z, f1.w);
    xb[gid] = st;
  }
}

extern "C" void kernel_launch(void* const* d_in, const int* in_sizes, int n_in,
                              void* d_out, int out_size, void* d_ws, size_t ws_size,
                              hipStream_t stream) {
  (void)in_sizes; (void)n_in; (void)out_size;
  const float* x    = (const float*)d_in[0];
  const int*   qw   = (const int*)d_in[1];
  const float* bias = (const float*)d_in[2];
  float* out = (float*)d_out;

  const size_t need = (size_t)Mdim * Kdim * 2;   // 4 MB bf16 fragment tiles
  if (ws_size >= need) {
    prep<true><<<1024, 256, 0, stream>>>(x, (uintx4*)d_ws, (floatx4*)out);
    q4k_gemm<true><<<512, 256, 0, stream>>>(x, (const bf16x8*)d_ws, qw, bias, out);
  } else {
    prep<false><<<1024, 256, 0, stream>>>(x, nullptr, (floatx4*)out);
    q4k_gemm<false><<<512, 256, 0, stream>>>(x, nullptr, qw, bias, out);
  }
}